// Round 16
// baseline (61.203 us; speedup 1.0000x reference)
//
#include <hip/hip_runtime.h>

// Batched Thomas tridiagonal solve, B=8192 rows, N=4096.
//   a_i = alpha[i-1]^2 (a_0=0); b_i = max(5+alpha[i]^3, 0.01);
//   c_i = alpha[i+1]^2 + 2*alpha[i+1]; rhs f (shared across rows).
//
// Chunked UL elimination with halos (right halo 8, left halo 8).
//
// R16: R15 retry — cvt_pkrtz returns __fp16 ext_vector(2); h2v retyped.
// Theory unchanged: gp/ep 80 f32 regs are the occupancy limiter (3 waves/
// SIMD); fp16-pack halves them -> 4 waves/SIMD. Carry chain stays f32.
// Added err ~1.3e-3 abs vs threshold 2.25e-2. Base: R13 (nt stores,
// two-tile pipeline, anti-sink fence).

namespace {
constexpr int kN   = 4096;
constexpr int kCH  = 32;              // outputs per lane
constexpr int kHL  = 8;               // left halo
constexpr int kR   = kCH + kHL;       // stored region = 40 (groups 0..9)
constexpr int kNC  = kN / kCH;        // 128
constexpr int RPW  = 8;               // rows per wave
constexpr int WAVES = 2;
constexpr int THREADS = 64 * WAVES;   // 128
constexpr int F4PR = 69;              // staged f4/row: cols [cb-12, cb+264)
constexpr int ST4  = 71;              // A row stride in f4 (284 dw; %32==28)
constexpr int APW4 = RPW * ST4;       // 568 f4 per wave A panel
constexpr int SF4  = 133;             // shared f pair window
constexpr int GHI  = 11;              // top group (halo groups 10..11)
}

using f4v = float __attribute__((ext_vector_type(4)));
using h2v = __fp16 __attribute__((ext_vector_type(2)));

__global__ __launch_bounds__(THREADS, 4) void thomas_v16(
    const float4* __restrict__ alpha4,
    const float4* __restrict__ f4,
    float4* __restrict__ u4)
{
  __shared__ float4 sM[WAVES * APW4 + SF4];   // 1269 f4 = 20304 B

  const int bid  = blockIdx.x;
  const int pair = bid & 7;                     // 512-col window pair
  const int r0   = (bid >> 3) * (WAVES * RPW);
  const int w    = threadIdx.x >> 6;
  const int lane = threadIdx.x & 63;
  const int rw0  = r0 + w * RPW;
  const int j    = lane & 7;                    // row-local (quarter-wave: 8 rows)
  const int q    = lane >> 3;                   // chunk-local 0..7

  float4* __restrict__ sA = sM + w * APW4;      // wave-private [RPW][ST4]
  float4* __restrict__ sF = sM + WAVES * APW4;  // block-shared f pair window

#define LOAD_TILE(cw, P)                                              \
  {                                                                   \
    const int cb4 = (cw) * 64 - 3;                                    \
    _Pragma("unroll")                                                 \
    for (int it = 0; it < 9; ++it) {                                  \
      int idx = lane + it * 64;                                       \
      if (idx > RPW * F4PR - 1) idx = RPW * F4PR - 1;  /* dup */      \
      const int row = idx / F4PR;                                     \
      const int c4  = idx - row * F4PR;                               \
      int g4 = cb4 + c4;                                              \
      g4 = (g4 < 0) ? 0 : ((g4 > 1023) ? 1023 : g4);  /* dups unused */ \
      P[it] = alpha4[(size_t)(rw0 + row) * 1024 + g4];                \
    }                                                                 \
  }

#define WRITE_TILE(P)                                                 \
  {                                                                   \
    _Pragma("unroll")                                                 \
    for (int it = 0; it < 9; ++it) {                                  \
      const int idx = lane + it * 64;                                 \
      if (idx < RPW * F4PR) {                                         \
        const int row = idx / F4PR;                                   \
        const int c4  = idx - row * F4PR;                             \
        sA[row * ST4 + c4] = P[it];                                   \
      }                                                               \
    }                                                                 \
  }

#define STEP(am1v, fiv)                                        \
  {                                                            \
    const float c_  = ap1 * (ap1 + 2.0f);                      \
    const float b_  = fmaxf(fmaf(a0 * a0, a0, 5.0f), 0.01f);   \
    const float dn  = fmaf(-c_, ec, b_);                       \
    const float rd  = __builtin_amdgcn_rcpf(dn);               \
    gc = (fiv - c_ * gc) * rd;                                 \
    ec = ((am1v) * (am1v)) * rd;                               \
    ap1 = a0; a0 = (am1v);                                     \
  }

  // Solve one tile from sA/sF; CWL is a compile-time 0/1.
#define SOLVE_TILE(CWL)                                                   \
  {                                                                       \
    const int  kk    = (pair * 2 + (CWL)) * 8 + q;                        \
    const bool first = (kk == 0);                                         \
    const bool last  = (kk == kNC - 1);                                   \
    const int  f4b   = first ? 3 : (q * 8 + 1);                           \
    const int  fOff  = (CWL) * 64;                                        \
    const float4* __restrict__ A4 = sA + j * ST4;                         \
    h2v gp_pk[kR / 2], ep_pk[kR / 2];   /* fp16-packed stores: 40 regs */ \
    float ec = 0.0f, gc = 0.0f, ap1 = 0.0f;                               \
    const int ghi = last ? 9 : GHI;                                       \
    float4 curA = A4[f4b + ghi];                                          \
    float4 lowA = A4[f4b + ghi - 1];                                      \
    float4 fcur = sF[fOff + f4b + ghi];                                   \
    float4 flow = sF[fOff + f4b + ghi - 1];                               \
    float a0 = curA.w;                                                    \
    if (!last) {                                                          \
      _Pragma("unroll")                                                   \
      for (int g = GHI; g >= 10; --g) {                                   \
        const float4 pA = A4[f4b + g - 2];                                \
        const float4 pF = sF[fOff + f4b + g - 2];                         \
        STEP(curA.z, fcur.w)                                              \
        STEP(curA.y, fcur.z)                                              \
        STEP(curA.x, fcur.y)                                              \
        STEP(lowA.w, fcur.x)                                              \
        curA = lowA; lowA = pA; fcur = flow; flow = pF;                   \
      }                                                                   \
    }                                                                     \
    _Pragma("unroll")                                                     \
    for (int g = 9; g >= 0; --g) {                                        \
      int pidx = f4b + g - 2;                                             \
      if (pidx < 0) pidx = 0;            /* value unused when clamped */  \
      const float4 pA = A4[pidx];                                         \
      const float4 pF = sF[fOff + pidx];                                  \
      float lw = lowA.w;                                                  \
      if (g == 0 && first) lw = 0.0f;    /* a_0 = 0 */                    \
      STEP(curA.z, fcur.w)  const float g3_ = gc, e3_ = ec;               \
      STEP(curA.y, fcur.z)  const float g2_ = gc, e2_ = ec;               \
      STEP(curA.x, fcur.y)  const float g1_ = gc, e1_ = ec;               \
      STEP(lw,     fcur.x)  const float g0_ = gc, e0_ = ec;               \
      gp_pk[2 * g + 1] = __builtin_amdgcn_cvt_pkrtz(g2_, g3_);            \
      gp_pk[2 * g]     = __builtin_amdgcn_cvt_pkrtz(g0_, g1_);            \
      ep_pk[2 * g + 1] = __builtin_amdgcn_cvt_pkrtz(e2_, e3_);            \
      ep_pk[2 * g]     = __builtin_amdgcn_cvt_pkrtz(e0_, e1_);            \
      curA = lowA; lowA = pA; fcur = flow; flow = pF;                     \
    }                                                                     \
    const int tmin = first ? 0 : kHL;                                     \
    float up = 0.0f;                                                      \
    float4 pk;                                                            \
    _Pragma("unroll")                                                     \
    for (int t = 0; t < kR; ++t) {                                        \
      const float gpv = (float)gp_pk[t >> 1][t & 1];                      \
      const float epv = (float)ep_pk[t >> 1][t & 1];                      \
      const float uv = fmaf(-epv, up, gpv);                               \
      up = uv;                                                            \
      const int ph = t & 3;                                               \
      if      (ph == 0) pk.x = uv;                                        \
      else if (ph == 1) pk.y = uv;                                        \
      else if (ph == 2) pk.z = uv;                                        \
      else {                                                              \
        pk.w = uv;                                                        \
        if (t - 3 >= tmin && t < tmin + kCH) {                            \
          sA[j * ST4 + q * 8 + ((t - 3 - tmin) >> 2)] = pk;               \
        }                                                                 \
      }                                                                   \
    }                                                                     \
    _Pragma("unroll")                                                     \
    for (int it = 0; it < RPW; ++it) {                                    \
      const float4 v = sA[it * ST4 + lane];                               \
      f4v vv; vv.x = v.x; vv.y = v.y; vv.z = v.z; vv.w = v.w;             \
      __builtin_nontemporal_store(vv, reinterpret_cast<f4v*>(             \
          u4 + (size_t)(rw0 + it) * 1024 + (pair * 2 + (CWL)) * 64 + lane)); \
    }                                                                     \
  }

  // ---- shared f window (idempotent writes by both waves; no barrier) ----
  {
    const int fb4 = pair * 128 - 3;
    #pragma unroll
    for (int it = 0; it < 3; ++it) {
      const int idx = lane + it * 64;
      if (idx < SF4) {
        int g4 = fb4 + idx;
        g4 = (g4 < 0) ? 0 : ((g4 > 1023) ? 1023 : g4);
        sF[idx] = f4[g4];
      }
    }
  }

  // ---- two-tile pipeline with pinned prefetch ----
  float4 p0[9];
  LOAD_TILE(pair * 2, p0)
  WRITE_TILE(p0)

  float4 p1[9];
  LOAD_TILE(pair * 2 + 1, p1)   // issued BEFORE T0 compute
  asm volatile("" ::: "memory"); // anti-sink fence

  SOLVE_TILE(0)                 // compute + subst + dump T0

  WRITE_TILE(p1)                // vmcnt wait for p1 lands here

  SOLVE_TILE(1)

#undef LOAD_TILE
#undef WRITE_TILE
#undef STEP
#undef SOLVE_TILE
}

extern "C" void kernel_launch(void* const* d_in, const int* in_sizes, int n_in,
                              void* d_out, int out_size, void* d_ws, size_t ws_size,
                              hipStream_t stream) {
  const float4* alpha = (const float4*)d_in[0];
  const float4* f     = (const float4*)d_in[1];
  float4*       uo    = (float4*)d_out;
  // grid: 512 row-groups (16 rows) x 8 window-pairs (512 cols) = 4096 blocks
  thomas_v16<<<dim3(4096), THREADS, 0, stream>>>(alpha, f, uo);
}

// Round 17
// 51.531 us; speedup vs baseline: 1.1877x; 1.1877x over previous
//
#include <hip/hip_runtime.h>

// Batched Thomas tridiagonal solve, B=8192 rows, N=4096.
//   a_i = alpha[i-1]^2 (a_0=0); b_i = max(5+alpha[i]^3, 0.01);
//   c_i = alpha[i+1]^2 + 2*alpha[i+1]; rhs f (shared across rows).
//
// Chunked UL elimination with halos (right halo 8, left halo 8).
//
// R17: R16 with launch_bounds(128,3). R11/R16 both regressed with the SAME
// spill signature (WRITE 131072->161792 KB, VGPR forced to 64): the ",4"
// bound imposes a 128-reg budget the allocator meets by spilling arrays to
// scratch. fp16-packed state is ~112 regs -- it fits 128 NATURALLY. Hint 3
// removes the forcing; allocation ~112 lands in the (64,128] granule -> 4
// waves/SIMD spill-free. Everything else identical to R16.

namespace {
constexpr int kN   = 4096;
constexpr int kCH  = 32;              // outputs per lane
constexpr int kHL  = 8;               // left halo
constexpr int kR   = kCH + kHL;       // stored region = 40 (groups 0..9)
constexpr int kNC  = kN / kCH;        // 128
constexpr int RPW  = 8;               // rows per wave
constexpr int WAVES = 2;
constexpr int THREADS = 64 * WAVES;   // 128
constexpr int F4PR = 69;              // staged f4/row: cols [cb-12, cb+264)
constexpr int ST4  = 71;              // A row stride in f4 (284 dw; %32==28)
constexpr int APW4 = RPW * ST4;       // 568 f4 per wave A panel
constexpr int SF4  = 133;             // shared f pair window
constexpr int GHI  = 11;              // top group (halo groups 10..11)
}

using f4v = float __attribute__((ext_vector_type(4)));
using h2v = __fp16 __attribute__((ext_vector_type(2)));

__global__ __launch_bounds__(THREADS, 3) void thomas_v17(
    const float4* __restrict__ alpha4,
    const float4* __restrict__ f4,
    float4* __restrict__ u4)
{
  __shared__ float4 sM[WAVES * APW4 + SF4];   // 1269 f4 = 20304 B

  const int bid  = blockIdx.x;
  const int pair = bid & 7;                     // 512-col window pair
  const int r0   = (bid >> 3) * (WAVES * RPW);
  const int w    = threadIdx.x >> 6;
  const int lane = threadIdx.x & 63;
  const int rw0  = r0 + w * RPW;
  const int j    = lane & 7;                    // row-local (quarter-wave: 8 rows)
  const int q    = lane >> 3;                   // chunk-local 0..7

  float4* __restrict__ sA = sM + w * APW4;      // wave-private [RPW][ST4]
  float4* __restrict__ sF = sM + WAVES * APW4;  // block-shared f pair window

#define LOAD_TILE(cw, P)                                              \
  {                                                                   \
    const int cb4 = (cw) * 64 - 3;                                    \
    _Pragma("unroll")                                                 \
    for (int it = 0; it < 9; ++it) {                                  \
      int idx = lane + it * 64;                                       \
      if (idx > RPW * F4PR - 1) idx = RPW * F4PR - 1;  /* dup */      \
      const int row = idx / F4PR;                                     \
      const int c4  = idx - row * F4PR;                               \
      int g4 = cb4 + c4;                                              \
      g4 = (g4 < 0) ? 0 : ((g4 > 1023) ? 1023 : g4);  /* dups unused */ \
      P[it] = alpha4[(size_t)(rw0 + row) * 1024 + g4];                \
    }                                                                 \
  }

#define WRITE_TILE(P)                                                 \
  {                                                                   \
    _Pragma("unroll")                                                 \
    for (int it = 0; it < 9; ++it) {                                  \
      const int idx = lane + it * 64;                                 \
      if (idx < RPW * F4PR) {                                         \
        const int row = idx / F4PR;                                   \
        const int c4  = idx - row * F4PR;                             \
        sA[row * ST4 + c4] = P[it];                                   \
      }                                                               \
    }                                                                 \
  }

#define STEP(am1v, fiv)                                        \
  {                                                            \
    const float c_  = ap1 * (ap1 + 2.0f);                      \
    const float b_  = fmaxf(fmaf(a0 * a0, a0, 5.0f), 0.01f);   \
    const float dn  = fmaf(-c_, ec, b_);                       \
    const float rd  = __builtin_amdgcn_rcpf(dn);               \
    gc = (fiv - c_ * gc) * rd;                                 \
    ec = ((am1v) * (am1v)) * rd;                               \
    ap1 = a0; a0 = (am1v);                                     \
  }

  // Solve one tile from sA/sF; CWL is a compile-time 0/1.
#define SOLVE_TILE(CWL)                                                   \
  {                                                                       \
    const int  kk    = (pair * 2 + (CWL)) * 8 + q;                        \
    const bool first = (kk == 0);                                         \
    const bool last  = (kk == kNC - 1);                                   \
    const int  f4b   = first ? 3 : (q * 8 + 1);                           \
    const int  fOff  = (CWL) * 64;                                        \
    const float4* __restrict__ A4 = sA + j * ST4;                         \
    h2v gp_pk[kR / 2], ep_pk[kR / 2];   /* fp16-packed stores: 40 regs */ \
    float ec = 0.0f, gc = 0.0f, ap1 = 0.0f;                               \
    const int ghi = last ? 9 : GHI;                                       \
    float4 curA = A4[f4b + ghi];                                          \
    float4 lowA = A4[f4b + ghi - 1];                                      \
    float4 fcur = sF[fOff + f4b + ghi];                                   \
    float4 flow = sF[fOff + f4b + ghi - 1];                               \
    float a0 = curA.w;                                                    \
    if (!last) {                                                          \
      _Pragma("unroll")                                                   \
      for (int g = GHI; g >= 10; --g) {                                   \
        const float4 pA = A4[f4b + g - 2];                                \
        const float4 pF = sF[fOff + f4b + g - 2];                         \
        STEP(curA.z, fcur.w)                                              \
        STEP(curA.y, fcur.z)                                              \
        STEP(curA.x, fcur.y)                                              \
        STEP(lowA.w, fcur.x)                                              \
        curA = lowA; lowA = pA; fcur = flow; flow = pF;                   \
      }                                                                   \
    }                                                                     \
    _Pragma("unroll")                                                     \
    for (int g = 9; g >= 0; --g) {                                        \
      int pidx = f4b + g - 2;                                             \
      if (pidx < 0) pidx = 0;            /* value unused when clamped */  \
      const float4 pA = A4[pidx];                                         \
      const float4 pF = sF[fOff + pidx];                                  \
      float lw = lowA.w;                                                  \
      if (g == 0 && first) lw = 0.0f;    /* a_0 = 0 */                    \
      STEP(curA.z, fcur.w)  const float g3_ = gc, e3_ = ec;               \
      STEP(curA.y, fcur.z)  const float g2_ = gc, e2_ = ec;               \
      STEP(curA.x, fcur.y)  const float g1_ = gc, e1_ = ec;               \
      STEP(lw,     fcur.x)  const float g0_ = gc, e0_ = ec;               \
      gp_pk[2 * g + 1] = __builtin_amdgcn_cvt_pkrtz(g2_, g3_);            \
      gp_pk[2 * g]     = __builtin_amdgcn_cvt_pkrtz(g0_, g1_);            \
      ep_pk[2 * g + 1] = __builtin_amdgcn_cvt_pkrtz(e2_, e3_);            \
      ep_pk[2 * g]     = __builtin_amdgcn_cvt_pkrtz(e0_, e1_);            \
      curA = lowA; lowA = pA; fcur = flow; flow = pF;                     \
    }                                                                     \
    const int tmin = first ? 0 : kHL;                                     \
    float up = 0.0f;                                                      \
    float4 pk;                                                            \
    _Pragma("unroll")                                                     \
    for (int t = 0; t < kR; ++t) {                                        \
      const float gpv = (float)gp_pk[t >> 1][t & 1];                      \
      const float epv = (float)ep_pk[t >> 1][t & 1];                      \
      const float uv = fmaf(-epv, up, gpv);                               \
      up = uv;                                                            \
      const int ph = t & 3;                                               \
      if      (ph == 0) pk.x = uv;                                        \
      else if (ph == 1) pk.y = uv;                                        \
      else if (ph == 2) pk.z = uv;                                        \
      else {                                                              \
        pk.w = uv;                                                        \
        if (t - 3 >= tmin && t < tmin + kCH) {                            \
          sA[j * ST4 + q * 8 + ((t - 3 - tmin) >> 2)] = pk;               \
        }                                                                 \
      }                                                                   \
    }                                                                     \
    _Pragma("unroll")                                                     \
    for (int it = 0; it < RPW; ++it) {                                    \
      const float4 v = sA[it * ST4 + lane];                               \
      f4v vv; vv.x = v.x; vv.y = v.y; vv.z = v.z; vv.w = v.w;             \
      __builtin_nontemporal_store(vv, reinterpret_cast<f4v*>(             \
          u4 + (size_t)(rw0 + it) * 1024 + (pair * 2 + (CWL)) * 64 + lane)); \
    }                                                                     \
  }

  // ---- shared f window (idempotent writes by both waves; no barrier) ----
  {
    const int fb4 = pair * 128 - 3;
    #pragma unroll
    for (int it = 0; it < 3; ++it) {
      const int idx = lane + it * 64;
      if (idx < SF4) {
        int g4 = fb4 + idx;
        g4 = (g4 < 0) ? 0 : ((g4 > 1023) ? 1023 : g4);
        sF[idx] = f4[g4];
      }
    }
  }

  // ---- two-tile pipeline with pinned prefetch ----
  float4 p0[9];
  LOAD_TILE(pair * 2, p0)
  WRITE_TILE(p0)

  float4 p1[9];
  LOAD_TILE(pair * 2 + 1, p1)   // issued BEFORE T0 compute
  asm volatile("" ::: "memory"); // anti-sink fence

  SOLVE_TILE(0)                 // compute + subst + dump T0

  WRITE_TILE(p1)                // vmcnt wait for p1 lands here

  SOLVE_TILE(1)

#undef LOAD_TILE
#undef WRITE_TILE
#undef STEP
#undef SOLVE_TILE
}

extern "C" void kernel_launch(void* const* d_in, const int* in_sizes, int n_in,
                              void* d_out, int out_size, void* d_ws, size_t ws_size,
                              hipStream_t stream) {
  const float4* alpha = (const float4*)d_in[0];
  const float4* f     = (const float4*)d_in[1];
  float4*       uo    = (float4*)d_out;
  // grid: 512 row-groups (16 rows) x 8 window-pairs (512 cols) = 4096 blocks
  thomas_v17<<<dim3(4096), THREADS, 0, stream>>>(alpha, f, uo);
}

// Round 18
// 48.198 us; speedup vs baseline: 1.2698x; 1.0691x over previous
//
#include <hip/hip_runtime.h>

// Batched Thomas tridiagonal solve, B=8192 rows, N=4096.
//   a_i = alpha[i-1]^2 (a_0=0); b_i = max(5+alpha[i]^3, 0.01);
//   c_i = alpha[i+1]^2 + 2*alpha[i+1]; rhs f (shared across rows).
//
// Chunked UL elimination with halos (right halo 8, left halo 8).
//
// R18: the natural-fit <=128-reg config. Occupancy steps at alloc {64,128,
// 256} (m69). R13 ~150 regs -> 2/SIMD; R16 forced 128 -> spill; R17 packed
// but kept the 36-reg p1 prefetch -> still >128 -> no gain. Now: ONE tile
// per wave (wave w takes window 2*pair+w, block = 2 waves x 8 shared rows),
// NO register prefetch (R9 proved it neutral), fp16-packed gp/ep. Demand
// ~105-115 regs -> 4 waves/SIMD; LDS 20304B x 8 blocks = 158.6KB/CU.
// Staging stall covered by 2x TLP. Math identical to R16/R17 (absmax
// anchor 0.0078125).

namespace {
constexpr int kCH  = 32;              // outputs per lane
constexpr int kHL  = 8;               // left halo
constexpr int kR   = kCH + kHL;       // stored region = 40 (groups 0..9)
constexpr int kNC  = 128;             // chunks per row
constexpr int RPW  = 8;               // rows per block (shared by both waves)
constexpr int THREADS = 128;          // 2 waves
constexpr int F4PR = 69;              // staged f4/row: cols [cb-12, cb+264)
constexpr int ST4  = 71;              // A row stride in f4 (284 dw; %32==28)
constexpr int APW4 = RPW * ST4;       // 568 f4 per wave panel
constexpr int SF4  = 133;             // shared f pair window
constexpr int GHI  = 11;              // top group (halo groups 10..11)
}

using f4v = float __attribute__((ext_vector_type(4)));
using h2v = __fp16 __attribute__((ext_vector_type(2)));

__global__ __launch_bounds__(THREADS, 3) void thomas_v18(
    const float4* __restrict__ alpha4,
    const float4* __restrict__ f4,
    float4* __restrict__ u4)
{
  __shared__ float4 sM[2 * APW4 + SF4];   // 1269 f4 = 20304 B

  const int bid  = blockIdx.x;
  const int pair = bid & 7;                 // 512-col window pair
  const int rw0  = (bid >> 3) * RPW;        // 8 rows, shared by both waves
  const int w    = threadIdx.x >> 6;        // wave id: tile 2*pair+w
  const int lane = threadIdx.x & 63;
  const int j    = lane & 7;                // row-local (quarter-wave: 8 rows)
  const int q    = lane >> 3;               // chunk-local 0..7
  const int cw   = pair * 2 + w;            // this wave's 256-col window

  float4* __restrict__ sA = sM + w * APW4;  // wave-private [RPW][ST4]
  float4* __restrict__ sF = sM + 2 * APW4;  // f pair window (idempotent writes)

  // ---- stage f window (each wave writes all of it; identical values) ----
  {
    const int fb4 = pair * 128 - 3;
    #pragma unroll
    for (int it = 0; it < 3; ++it) {
      const int idx = lane + it * 64;
      if (idx < SF4) {
        int g4 = fb4 + idx;
        g4 = (g4 < 0) ? 0 : ((g4 > 1023) ? 1023 : g4);
        sF[idx] = f4[g4];
      }
    }
  }

  // ---- stage own alpha panel; unroll capped at 3 to limit live loads ----
  {
    const int cb4 = cw * 64 - 3;
    #pragma unroll 3
    for (int it = 0; it < 9; ++it) {
      int idx = lane + it * 64;
      if (idx > RPW * F4PR - 1) idx = RPW * F4PR - 1;   // dup, unused
      const int row = idx / F4PR;
      const int c4  = idx - row * F4PR;
      int g4 = cb4 + c4;
      g4 = (g4 < 0) ? 0 : ((g4 > 1023) ? 1023 : g4);    // dups unused
      sA[row * ST4 + c4] = alpha4[(size_t)(rw0 + row) * 1024 + g4];
    }
  }
  // no __syncthreads: wave reads only its own sA + its own sF writes
  // (lockstep + lgkmcnt ordering)

#define STEP(am1v, fiv)                                        \
  {                                                            \
    const float c_  = ap1 * (ap1 + 2.0f);                      \
    const float b_  = fmaxf(fmaf(a0 * a0, a0, 5.0f), 0.01f);   \
    const float dn  = fmaf(-c_, ec, b_);                       \
    const float rd  = __builtin_amdgcn_rcpf(dn);               \
    gc = (fiv - c_ * gc) * rd;                                 \
    ec = ((am1v) * (am1v)) * rd;                               \
    ap1 = a0; a0 = (am1v);                                     \
  }

  // ---- solve this wave's tile ----
  const int  kk    = cw * 8 + q;
  const bool first = (kk == 0);
  const bool last  = (kk == kNC - 1);
  const int  f4b   = first ? 3 : (q * 8 + 1);
  const int  fOff  = w * 64;
  const float4* __restrict__ A4 = sA + j * ST4;

  h2v gp_pk[kR / 2], ep_pk[kR / 2];     // fp16-packed stores: 40 regs
  float ec = 0.0f, gc = 0.0f, ap1 = 0.0f;
  const int ghi = last ? 9 : GHI;
  float4 curA = A4[f4b + ghi];
  float4 lowA = A4[f4b + ghi - 1];
  float4 fcur = sF[fOff + f4b + ghi];
  float4 flow = sF[fOff + f4b + ghi - 1];
  float a0 = curA.w;

  if (!last) {
    #pragma unroll
    for (int g = GHI; g >= 10; --g) {
      const float4 pA = A4[f4b + g - 2];
      const float4 pF = sF[fOff + f4b + g - 2];
      STEP(curA.z, fcur.w)
      STEP(curA.y, fcur.z)
      STEP(curA.x, fcur.y)
      STEP(lowA.w, fcur.x)
      curA = lowA; lowA = pA; fcur = flow; flow = pF;
    }
  }

  #pragma unroll
  for (int g = 9; g >= 0; --g) {
    int pidx = f4b + g - 2;
    if (pidx < 0) pidx = 0;              // value unused when clamped
    const float4 pA = A4[pidx];
    const float4 pF = sF[fOff + pidx];
    float lw = lowA.w;
    if (g == 0 && first) lw = 0.0f;      // a_0 = 0
    STEP(curA.z, fcur.w)  const float g3_ = gc, e3_ = ec;
    STEP(curA.y, fcur.z)  const float g2_ = gc, e2_ = ec;
    STEP(curA.x, fcur.y)  const float g1_ = gc, e1_ = ec;
    STEP(lw,     fcur.x)  const float g0_ = gc, e0_ = ec;
    gp_pk[2 * g + 1] = __builtin_amdgcn_cvt_pkrtz(g2_, g3_);
    gp_pk[2 * g]     = __builtin_amdgcn_cvt_pkrtz(g0_, g1_);
    ep_pk[2 * g + 1] = __builtin_amdgcn_cvt_pkrtz(e2_, e3_);
    ep_pk[2 * g]     = __builtin_amdgcn_cvt_pkrtz(e0_, e1_);
    curA = lowA; lowA = pA; fcur = flow; flow = pF;
  }

  // ---- substitution into own panel (overlays sA), then nt dump ----
  const int tmin = first ? 0 : kHL;
  float up = 0.0f;
  float4 pk;
  #pragma unroll
  for (int t = 0; t < kR; ++t) {
    const float gpv = (float)gp_pk[t >> 1][t & 1];
    const float epv = (float)ep_pk[t >> 1][t & 1];
    const float uv = fmaf(-epv, up, gpv);
    up = uv;
    const int ph = t & 3;
    if      (ph == 0) pk.x = uv;
    else if (ph == 1) pk.y = uv;
    else if (ph == 2) pk.z = uv;
    else {
      pk.w = uv;
      if (t - 3 >= tmin && t < tmin + kCH) {
        sA[j * ST4 + q * 8 + ((t - 3 - tmin) >> 2)] = pk;
      }
    }
  }

  #pragma unroll
  for (int it = 0; it < RPW; ++it) {
    const float4 v = sA[it * ST4 + lane];
    f4v vv; vv.x = v.x; vv.y = v.y; vv.z = v.z; vv.w = v.w;
    __builtin_nontemporal_store(vv, reinterpret_cast<f4v*>(
        u4 + (size_t)(rw0 + it) * 1024 + cw * 64 + lane));
  }

#undef STEP
}

extern "C" void kernel_launch(void* const* d_in, const int* in_sizes, int n_in,
                              void* d_out, int out_size, void* d_ws, size_t ws_size,
                              hipStream_t stream) {
  const float4* alpha = (const float4*)d_in[0];
  const float4* f     = (const float4*)d_in[1];
  float4*       uo    = (float4*)d_out;
  // grid: 1024 row-groups (8 rows) x 8 window-pairs (512 cols) = 8192 blocks
  thomas_v18<<<dim3(8192), THREADS, 0, stream>>>(alpha, f, uo);
}